// Round 2
// baseline (113822.034 us; speedup 1.0000x reference)
//
#include <hip/hip_runtime.h>
#include <math.h>

// ---- workspace layout (float units) ----
#define WN_OFF    0          // 512*3072 filtered noise, [t][n]
#define THBUF_OFF 1572864    // 2 * 32*3072 fp32 tanh(h), [parity][b][n]
#define THT_OFF   1769472    // 2 * 3072*32 fp32 tanh(h) transposed, [parity][n][b]
#define XT_OFF    1966080    // 512*512 fp32 x transposed, [t][b*16+i]
#define BAR_OFF   2228224    // 2 uints: barrier counter, generation
// ---- output layout (float units) ----
#define Y0_OFF    50331648   // H is [0, 50331648): [b][n][t]
#define YR0_OFF   50348032   // yr: [b][rr][mm][t]

// prep: x transpose -> xT[t][b*16+i], th0 (both layouts), barrier init
__global__ void prep1(const float* __restrict__ x,
                      const float* __restrict__ h0,
                      float* __restrict__ ws) {
  int i = blockIdx.x * blockDim.x + threadIdx.x;
  const int stride = gridDim.x * blockDim.x;
  const int NXT = 512 * 512;
  const int NTH0 = 32 * 3072;
  for (; i < NXT + NTH0 + 2; i += stride) {
    if (i < NXT) {
      int t = i >> 9, bi = i & 511;
      ws[XT_OFF + i] = x[bi * 512 + t];   // x[b][i][t] at (b*16+i)*512+t
    } else if (i < NXT + NTH0) {
      int e = i - NXT;
      int b = e / 3072, n = e - b * 3072;
      float v = tanhf(h0[e]);
      ws[THBUF_OFF + e] = v;
      ws[THT_OFF + n * 32 + b] = v;
    } else {
      ((unsigned*)(ws + BAR_OFF))[i - (NXT + NTH0)] = 0u;
    }
  }
}

// prep: filtered noise wn[t][n] = AMPWN * lowpass(sqrt(TAUWN)*iWN)
__global__ void prep2(const float* __restrict__ iwn,
                      float* __restrict__ ws) {
  int n = blockIdx.x * blockDim.x + threadIdx.x;
  if (n >= 3072) return;
  const float s10 = sqrtf(10.0f);
  const float a = expf(-0.1f);
  float prev = s10 * iwn[n * 512];
  ws[WN_OFF + n] = 0.01f * prev;
  for (int t = 1; t < 512; ++t) {
    float cur = s10 * iwn[n * 512 + t];
    prev = cur + (prev - cur) * a;
    ws[WN_OFF + t * 3072 + n] = 0.01f * prev;
  }
}

__device__ __forceinline__ void gridBarrier(unsigned* cnt, unsigned* gen) {
  __syncthreads();
  if (threadIdx.x == 0) {
    unsigned g0 = __hip_atomic_load(gen, __ATOMIC_RELAXED, __HIP_MEMORY_SCOPE_AGENT);
    unsigned a = __hip_atomic_fetch_add(cnt, 1u, __ATOMIC_ACQ_REL, __HIP_MEMORY_SCOPE_AGENT);
    if (a == 255u) {
      __hip_atomic_store(cnt, 0u, __ATOMIC_RELAXED, __HIP_MEMORY_SCOPE_AGENT);
      __hip_atomic_fetch_add(gen, 1u, __ATOMIC_ACQ_REL, __HIP_MEMORY_SCOPE_AGENT);
    } else {
      while (__hip_atomic_load(gen, __ATOMIC_ACQUIRE, __HIP_MEMORY_SCOPE_AGENT) == g0) {
        __builtin_amdgcn_s_sleep(2);
      }
    }
  }
  __syncthreads();
}

__global__ void __launch_bounds__(256) rnn_main(
    const float* __restrict__ Wih,
    const float* __restrict__ W11,
    const float* __restrict__ W22,
    const float* __restrict__ W33,
    const float* __restrict__ W12,
    const float* __restrict__ W23,
    const float* __restrict__ Who,
    const float* __restrict__ Whc2,
    const float* __restrict__ Wr1,
    const float* __restrict__ Wr2,
    const float* __restrict__ Wr3,
    const int* __restrict__ id12_1, const int* __restrict__ id12_2,
    const int* __restrict__ id23_2, const int* __restrict__ id23_3,
    const float* __restrict__ ctx,
    const float* __restrict__ h0,
    float* __restrict__ ws,
    float* __restrict__ out) {

  // static LDS: 16896 + 4096 + 1024 + 8192 + ~200 = ~30.4 KB
  __shared__ float th_lds[32 * 132];   // th chunk [b][128+pad4] (also aliased as scratch/auxb)
  __shared__ float coupf[1024];        // sparse coupling [ksplit][j16][b32]
  __shared__ float Wih_lds[256];       // [j16][i16]
  __shared__ float Hbuf[512 * 4];      // 4-step H accumulation, [j*32+b][4]
  __shared__ float ci16[16];
  __shared__ int ql_j[16], ql_q[16];
  __shared__ int nq_s;

  const int g = blockIdx.x;
  const int tid = threadIdx.x;
  unsigned* bar = (unsigned*)(ws + BAR_OFF);
  const int mmod = (g < 192) ? (g >> 6) : 0;
  const int loc0 = (g & 63) * 16;
  const int bb = tid & 15;
  const int jg = (tid >> 4) & 7;
  const int kh = tid >> 7;  // k-split half
  float h00 = 0.f, h01 = 0.f, h10 = 0.f, h11 = 0.f;

  const float* Wsrc = (mmod == 0) ? W11 : ((mmod == 1) ? W22 : W33);

  if (g < 192) {
    if (mmod == 0) {
      int jj = tid >> 4, ii = tid & 15;
      Wih_lds[tid] = Wih[(loc0 + jj) * 16 + ii];
    }
    if (mmod == 1 && tid < 16) {
      ci16[tid] = ctx[0] * Whc2[(loc0 + tid) * 2];
    }
    if (tid == 0) {
      int cnt = 0;
      if (mmod != 0) {
        const int* scat = (mmod == 1) ? id12_2 : id23_3;
        for (int q = 0; q < 205; ++q) {
          int jj = scat[q] - loc0;
          if (jj >= 0 && jj < 16) { ql_j[cnt] = jj; ql_q[cnt] = q; ++cnt; }
        }
      }
      nq_s = cnt;
    }
    if (!kh) {
      int gn0 = mmod * 1024 + loc0 + jg;
      h00 = h0[bb * 3072 + gn0];
      h01 = h0[(bb + 16) * 3072 + gn0];
      h10 = h0[bb * 3072 + gn0 + 8];
      h11 = h0[(bb + 16) * 3072 + gn0 + 8];
    }
  }
  __syncthreads();

  #pragma unroll 1
  for (int t = 0; t < 512; ++t) {
    const int p = t & 1;
    const float* thbuf_p = ws + THBUF_OFF + (size_t)p * 98304;
    float*       thbuf_n = ws + THBUF_OFF + (size_t)(p ^ 1) * 98304;
    const float* thT_p   = ws + THT_OFF + (size_t)p * 98304;
    float*       thT_n   = ws + THT_OFF + (size_t)(p ^ 1) * 98304;

    if (g < 192) {
      // ---- zero coupling staging ----
      #pragma unroll
      for (int i = 0; i < 4; ++i) coupf[tid * 4 + i] = 0.0f;
      __syncthreads();
      // ---- sparse couplings (gather via transposed th, coalesced over b) ----
      if (mmod != 0) {
        const int ntask = nq_s * 64;
        const float* Wsp = (mmod == 1) ? W12 : W23;
        const int* gidx = (mmod == 1) ? id12_1 : id23_2;
        const int rbase = (mmod == 1) ? 0 : 1024;
        for (int task = tid; task < ntask; task += 256) {
          int kh2 = task & 1;
          int b = (task >> 1) & 31;
          int qi = task >> 6;
          int q = ql_q[qi], jj = ql_j[qi];
          int p0 = kh2 ? 103 : 0;
          int p1 = kh2 ? 205 : 103;
          float v = 0.0f;
          for (int pp = p0; pp < p1; ++pp) {
            v += Wsp[q * 205 + pp] * thT_p[(rbase + gidx[pp]) * 32 + b];
          }
          coupf[kh2 * 512 + jj * 32 + b] = v;
        }
      }
      // ---- main GEMM: 16 neurons x 32 batch, K=1024, k-split by 2 ----
      float acc00 = 0.f, acc01 = 0.f, acc10 = 0.f, acc11 = 0.f;
      const float* thmod = thbuf_p + mmod * 1024;
      const int kb = kh * 64;
      #pragma unroll 1
      for (int c = 0; c < 8; ++c) {
        __syncthreads();
        #pragma unroll
        for (int i = 0; i < 4; ++i) {
          int idx = i * 1024 + tid * 4;
          int bl = idx >> 7, kl = idx & 127;
          float4 v = *(const float4*)(thmod + bl * 3072 + c * 128 + kl);
          *(float4*)&th_lds[bl * 132 + kl] = v;
        }
        __syncthreads();
        const float* wr0 = Wsrc + (size_t)(loc0 + jg) * 1024 + c * 128 + kb;
        const float* wr1 = Wsrc + (size_t)(loc0 + jg + 8) * 1024 + c * 128 + kb;
        #pragma unroll
        for (int kk = 0; kk < 64; kk += 8) {
          const int kl = kb + kk;             // chunk-local k (for th)
          float4 wa0 = *(const float4*)(wr0 + kk);
          float4 wa1 = *(const float4*)(wr0 + kk + 4);
          float4 wb0 = *(const float4*)(wr1 + kk);
          float4 wb1 = *(const float4*)(wr1 + kk + 4);
          float4 t0a = *(const float4*)&th_lds[bb * 132 + kl];
          float4 t0b = *(const float4*)&th_lds[bb * 132 + kl + 4];
          float4 t1a = *(const float4*)&th_lds[(bb + 16) * 132 + kl];
          float4 t1b = *(const float4*)&th_lds[(bb + 16) * 132 + kl + 4];
          float wva[8], wvb[8], tva[8], tvb[8];
          wva[0]=wa0.x; wva[1]=wa0.y; wva[2]=wa0.z; wva[3]=wa0.w;
          wva[4]=wa1.x; wva[5]=wa1.y; wva[6]=wa1.z; wva[7]=wa1.w;
          wvb[0]=wb0.x; wvb[1]=wb0.y; wvb[2]=wb0.z; wvb[3]=wb0.w;
          wvb[4]=wb1.x; wvb[5]=wb1.y; wvb[6]=wb1.z; wvb[7]=wb1.w;
          tva[0]=t0a.x; tva[1]=t0a.y; tva[2]=t0a.z; tva[3]=t0a.w;
          tva[4]=t0b.x; tva[5]=t0b.y; tva[6]=t0b.z; tva[7]=t0b.w;
          tvb[0]=t1a.x; tvb[1]=t1a.y; tvb[2]=t1a.z; tvb[3]=t1a.w;
          tvb[4]=t1b.x; tvb[5]=t1b.y; tvb[6]=t1b.z; tvb[7]=t1b.w;
          #pragma unroll
          for (int q = 0; q < 8; ++q) {
            acc00 += wva[q] * tva[q];
            acc01 += wva[q] * tvb[q];
            acc10 += wvb[q] * tva[q];
            acc11 += wvb[q] * tvb[q];
          }
        }
      }
      __syncthreads();
      float* scratchf = th_lds;  // safe alias: th_lds idle until next c-loop (post-sync)
      if (kh) {
        int l = (tid - 128) * 4;
        scratchf[l] = acc00; scratchf[l + 1] = acc01;
        scratchf[l + 2] = acc10; scratchf[l + 3] = acc11;
      }
      __syncthreads();
      if (!kh) {
        acc00 += scratchf[tid * 4];     acc01 += scratchf[tid * 4 + 1];
        acc10 += scratchf[tid * 4 + 2]; acc11 += scratchf[tid * 4 + 3];
        const float* xTt = ws + XT_OFF + t * 512;
        const float* wnt = ws + WN_OFF + t * 3072;
        float accs[4] = {acc00, acc01, acc10, acc11};
        float hs[4] = {h00, h01, h10, h11};
        #pragma unroll
        for (int js = 0; js < 2; ++js) {
          int j = jg + js * 8;
          int gn = mmod * 1024 + loc0 + j;
          #pragma unroll
          for (int bs = 0; bs < 2; ++bs) {
            int b = bb + bs * 16;
            float dot = accs[js * 2 + bs];
            float extra;
            if (mmod == 0) {
              extra = 0.f;
              #pragma unroll
              for (int ii = 0; ii < 16; ++ii)
                extra += xTt[b * 16 + ii] * Wih_lds[j * 16 + ii];
            } else {
              float cp = coupf[j * 32 + b] + coupf[512 + j * 32 + b];
              extra = (mmod == 1) ? cp * ci16[j] : cp;
            }
            float hv = hs[js * 2 + bs];
            hv = hv + (dot + extra + wnt[gn] - hv) / 10.0f;
            hs[js * 2 + bs] = hv;
            float tv = tanhf(hv);
            thbuf_n[b * 3072 + gn] = tv;
            thT_n[gn * 32 + b] = tv;
            Hbuf[(j * 32 + b) * 4 + (t & 3)] = tv;
          }
        }
        h00 = hs[0]; h01 = hs[1]; h10 = hs[2]; h11 = hs[3];
      }
      if ((t & 3) == 3) {   // burst H out as full 16B lines
        __syncthreads();
        #pragma unroll
        for (int r = 0; r < 2; ++r) {
          int o = tid * 2 + r;
          int j = o >> 5, b = o & 31;
          size_t gn = (size_t)(mmod * 1024 + loc0 + j);
          float4 v = *(const float4*)&Hbuf[o * 4];
          *(float4*)&out[((size_t)b * 3072 + gn) * 512 + (t - 3)] = v;
        }
      }
    } else {
      // ---- aux WGs: y and yr readouts (one wave per dot-block) ----
      const int w = tid >> 6, lane = tid & 63;
      const int gw = (g - 192) * 4 + w;  // 0..255
      float* auxb = th_lds;  // aux-only alias, 64 rows x 4 floats
      for (int s = 0; s < 4; ++s) {
        const int u = gw + s * 256;
        if (u >= 800) break;
        float a0 = 0.f, a1 = 0.f, a2 = 0.f, a3 = 0.f;
        if (u < 768) {
          const int mm = u >> 8;
          const int rem = u & 255;
          const int b = rem >> 3;
          const int rr0 = (rem & 7) * 4;
          const float* Wr = (mm == 0) ? Wr1 : ((mm == 1) ? Wr2 : Wr3);
          const float* trow = thbuf_p + b * 3072 + mm * 1024;
          #pragma unroll
          for (int it = 0; it < 4; ++it) {
            int k = it * 256 + lane * 4;
            float4 tv = *(const float4*)(trow + k);
            float4 q0 = *(const float4*)&Wr[(rr0 + 0) * 1024 + k];
            float4 q1 = *(const float4*)&Wr[(rr0 + 1) * 1024 + k];
            float4 q2 = *(const float4*)&Wr[(rr0 + 2) * 1024 + k];
            float4 q3 = *(const float4*)&Wr[(rr0 + 3) * 1024 + k];
            a0 += tv.x*q0.x + tv.y*q0.y + tv.z*q0.z + tv.w*q0.w;
            a1 += tv.x*q1.x + tv.y*q1.y + tv.z*q1.z + tv.w*q1.w;
            a2 += tv.x*q2.x + tv.y*q2.y + tv.z*q2.z + tv.w*q2.w;
            a3 += tv.x*q3.x + tv.y*q3.y + tv.z*q3.z + tv.w*q3.w;
          }
        } else {
          const int b = u - 768;
          const float* trow = thbuf_p + b * 3072 + 2048;
          #pragma unroll
          for (int it = 0; it < 4; ++it) {
            int k = it * 256 + lane * 4;
            float4 tv = *(const float4*)(trow + k);
            float4 q0 = *(const float4*)&Who[k];
            a0 += tv.x*q0.x + tv.y*q0.y + tv.z*q0.z + tv.w*q0.w;
          }
        }
        #pragma unroll
        for (int off = 32; off > 0; off >>= 1) {
          a0 += __shfl_xor(a0, off);
          a1 += __shfl_xor(a1, off);
          a2 += __shfl_xor(a2, off);
          a3 += __shfl_xor(a3, off);
        }
        if (lane == 0) {
          int base = ((w * 4 + s) * 4) * 4 + (t & 3);
          auxb[base] = tanhf(a0);
          if (u < 768) {
            auxb[base + 4]  = tanhf(a1);
            auxb[base + 8]  = tanhf(a2);
            auxb[base + 12] = tanhf(a3);
          }
        }
      }
      if ((t & 3) == 3) {
        int s = lane >> 2, rv = lane & 3;
        if (lane < 16) {
          int u = gw + s * 256;
          if (u < 768) {
            int mm = u >> 8, rem = u & 255, b = rem >> 3, rr = (rem & 7) * 4 + rv;
            float4 v = *(const float4*)&auxb[((w * 4 + s) * 4 + rv) * 4];
            *(float4*)&out[(size_t)YR0_OFF + ((size_t)(b * 32 + rr) * 3 + mm) * 512 + (t - 3)] = v;
          } else if (u < 800 && rv == 0) {
            float4 v = *(const float4*)&auxb[((w * 4 + s) * 4) * 4];
            *(float4*)&out[(size_t)Y0_OFF + (size_t)(u - 768) * 512 + (t - 3)] = v;
          }
        }
      }
    }
    gridBarrier(bar, bar + 1);
  }
}

extern "C" void kernel_launch(void* const* d_in, const int* in_sizes, int n_in,
                              void* d_out, int out_size, void* d_ws, size_t ws_size,
                              hipStream_t stream) {
  (void)in_sizes; (void)n_in; (void)out_size; (void)ws_size;
  const float* x    = (const float*)d_in[0];
  const float* h0   = (const float*)d_in[1];
  const float* ctx  = (const float*)d_in[2];
  const float* iWN  = (const float*)d_in[3];
  const float* Wih  = (const float*)d_in[4];
  const float* W11  = (const float*)d_in[5];
  const float* W22  = (const float*)d_in[6];
  const float* W33  = (const float*)d_in[7];
  const float* W12  = (const float*)d_in[8];
  const float* W23  = (const float*)d_in[9];
  const float* Who  = (const float*)d_in[10];
  const float* Whc2 = (const float*)d_in[11];
  const float* Wr1  = (const float*)d_in[12];
  const float* Wr2  = (const float*)d_in[13];
  const float* Wr3  = (const float*)d_in[14];
  const int* id12_1 = (const int*)d_in[15];
  const int* id12_2 = (const int*)d_in[16];
  const int* id23_2 = (const int*)d_in[17];
  const int* id23_3 = (const int*)d_in[18];
  float* ws = (float*)d_ws;
  float* out = (float*)d_out;

  hipLaunchKernelGGL(prep1, dim3(512), dim3(256), 0, stream, x, h0, ws);
  hipLaunchKernelGGL(prep2, dim3(12), dim3(256), 0, stream, iWN, ws);
  hipLaunchKernelGGL(rnn_main, dim3(256), dim3(256), 0, stream,
                     Wih, W11, W22, W33, W12, W23, Who, Whc2, Wr1, Wr2, Wr3,
                     id12_1, id12_2, id23_2, id23_3, ctx, h0, ws, out);
}

// Round 3
// 51266.394 us; speedup vs baseline: 2.2202x; 2.2202x over previous
//
#include <hip/hip_runtime.h>
#include <math.h>

// ---- workspace layout (float units) ----
#define WN_OFF    0          // 512*3072 filtered noise, [t][n]
#define THBUF_OFF 1572864    // 2 * 32*3072 fp32 tanh(h), [parity][b][n]
#define THT_OFF   1769472    // 2 * 3072*32 fp32 tanh(h) transposed, [parity][n][b]
#define XT_OFF    1966080    // 512*512 fp32 x transposed, [t][b*16+i]
#define BAR_OFF   2228224    // flags: 256 * 16 uints (64B spaced) + gen at [4096]
// ---- output layout (float units) ----
#define Y0_OFF    50331648
#define YR0_OFF   50348032
#define MASTER    255

// ---- dynamic LDS layout (float units) ----
#define L_W      0            // 16*1028 = 16448
#define L_TH     16448        // 2*32*260 = 16640
#define L_COUP   33088        // 1024 (aux WGs alias this as auxb)
#define L_WIH    34112        // 256
#define L_HBUF   34368        // 2048
#define L_RED    36416        // 1024
#define L_CI     37440        // 16
#define L_GIDX   37456        // 208 ints
#define L_QLJ    37664        // 16 ints
#define L_QLQ    37680        // 16 ints
#define L_NQ     37696        // 1 int
#define SMEM_FLOATS 37760
#define SMEM_BYTES  (SMEM_FLOATS * 4)

__global__ void prep1(const float* __restrict__ x,
                      const float* __restrict__ h0,
                      float* __restrict__ ws) {
  int i = blockIdx.x * blockDim.x + threadIdx.x;
  const int stride = gridDim.x * blockDim.x;
  const int NXT = 512 * 512;
  const int NTH0 = 32 * 3072;
  const int NBAR = 4097;
  for (; i < NXT + NTH0 + NBAR; i += stride) {
    if (i < NXT) {
      int t = i >> 9, bi = i & 511;
      ws[XT_OFF + i] = x[bi * 512 + t];
    } else if (i < NXT + NTH0) {
      int e = i - NXT;
      int b = e / 3072, n = e - b * 3072;
      float v = tanhf(h0[e]);
      ws[THBUF_OFF + e] = v;
      ws[THT_OFF + n * 32 + b] = v;
    } else {
      ((unsigned*)(ws + BAR_OFF))[i - (NXT + NTH0)] = 0u;
    }
  }
}

__global__ void prep2(const float* __restrict__ iwn,
                      float* __restrict__ ws) {
  int n = blockIdx.x * blockDim.x + threadIdx.x;
  if (n >= 3072) return;
  const float s10 = sqrtf(10.0f);
  const float a = expf(-0.1f);
  float prev = s10 * iwn[n * 512];
  ws[WN_OFF + n] = 0.01f * prev;
  for (int t = 1; t < 512; ++t) {
    float cur = s10 * iwn[n * 512 + t];
    prev = cur + (prev - cur) * a;
    ws[WN_OFF + t * 3072 + n] = 0.01f * prev;
  }
}

// Flag-array barrier: per-WG release-store to own line; master polls all,
// publishes generation. No contended RMW anywhere.
__device__ __forceinline__ void flagBarrier(unsigned* flags, unsigned* gen,
                                            int g, int tid, unsigned tv) {
  __syncthreads();
  if (tid == 0)
    __hip_atomic_store(&flags[g * 16], tv, __ATOMIC_RELEASE, __HIP_MEMORY_SCOPE_AGENT);
  if (g == MASTER) {
    while (__hip_atomic_load(&flags[tid * 16], __ATOMIC_RELAXED,
                             __HIP_MEMORY_SCOPE_AGENT) < tv)
      __builtin_amdgcn_s_sleep(1);
    __syncthreads();
    __builtin_amdgcn_fence(__ATOMIC_ACQUIRE, "agent");
    if (tid == 0)
      __hip_atomic_store(gen, tv, __ATOMIC_RELEASE, __HIP_MEMORY_SCOPE_AGENT);
  } else {
    if (tid == 0) {
      while (__hip_atomic_load(gen, __ATOMIC_RELAXED,
                               __HIP_MEMORY_SCOPE_AGENT) < tv)
        __builtin_amdgcn_s_sleep(1);
    }
    __syncthreads();
    __builtin_amdgcn_fence(__ATOMIC_ACQUIRE, "agent");
  }
}

#define LOADPF(c_) do { \
  const float* src_ = thmod + (c_) * 256; \
  _Pragma("unroll") \
  for (int i_ = 0; i_ < 8; ++i_) { \
    int e_ = i_ * 1024 + tid * 4; \
    pf[i_] = *(const float4*)(src_ + (e_ >> 8) * 3072 + (e_ & 255)); \
  } } while (0)

#define WRITEBUF(c_) do { \
  float* dst_ = th_base + ((c_) & 1) * 8320; \
  _Pragma("unroll") \
  for (int i_ = 0; i_ < 8; ++i_) { \
    int e_ = i_ * 1024 + tid * 4; \
    *(float4*)(dst_ + (e_ >> 8) * 260 + (e_ & 255)) = pf[i_]; \
  } } while (0)

#define COMPUTE_CHUNK(c_) do { \
  const float* tb_ = th_base + ((c_) & 1) * 8320; \
  const float* t0_ = tb_ + bb * 260 + kb; \
  const float* t1_ = t0_ + 4160; \
  const float* w0_ = W_lds + jg * 1028 + (c_) * 256 + kb; \
  const float* w1_ = w0_ + 8224; \
  _Pragma("unroll") \
  for (int kk = 0; kk < 128; kk += 8) { \
    float4 wa0 = *(const float4*)(w0_ + kk); \
    float4 wa1 = *(const float4*)(w0_ + kk + 4); \
    float4 wb0 = *(const float4*)(w1_ + kk); \
    float4 wb1 = *(const float4*)(w1_ + kk + 4); \
    float4 t0a = *(const float4*)(t0_ + kk); \
    float4 t0b = *(const float4*)(t0_ + kk + 4); \
    float4 t1a = *(const float4*)(t1_ + kk); \
    float4 t1b = *(const float4*)(t1_ + kk + 4); \
    acc00 += wa0.x*t0a.x + wa0.y*t0a.y + wa0.z*t0a.z + wa0.w*t0a.w \
           + wa1.x*t0b.x + wa1.y*t0b.y + wa1.z*t0b.z + wa1.w*t0b.w; \
    acc01 += wa0.x*t1a.x + wa0.y*t1a.y + wa0.z*t1a.z + wa0.w*t1a.w \
           + wa1.x*t1b.x + wa1.y*t1b.y + wa1.z*t1b.z + wa1.w*t1b.w; \
    acc10 += wb0.x*t0a.x + wb0.y*t0a.y + wb0.z*t0a.z + wb0.w*t0a.w \
           + wb1.x*t0b.x + wb1.y*t0b.y + wb1.z*t0b.z + wb1.w*t0b.w; \
    acc11 += wb0.x*t1a.x + wb0.y*t1a.y + wb0.z*t1a.z + wb0.w*t1a.w \
           + wb1.x*t1b.x + wb1.y*t1b.y + wb1.z*t1b.z + wb1.w*t1b.w; \
  } } while (0)

__global__ void __launch_bounds__(256, 1) rnn_main(
    const float* __restrict__ Wih,
    const float* __restrict__ W11,
    const float* __restrict__ W22,
    const float* __restrict__ W33,
    const float* __restrict__ W12,
    const float* __restrict__ W23,
    const float* __restrict__ Who,
    const float* __restrict__ Whc2,
    const float* __restrict__ Wr1,
    const float* __restrict__ Wr2,
    const float* __restrict__ Wr3,
    const int* __restrict__ id12_1, const int* __restrict__ id12_2,
    const int* __restrict__ id23_2, const int* __restrict__ id23_3,
    const float* __restrict__ ctx,
    const float* __restrict__ h0,
    float* __restrict__ ws,
    float* __restrict__ out) {

  extern __shared__ float smem[];
  float* W_lds   = smem + L_W;
  float* th_base = smem + L_TH;
  float* coupf   = smem + L_COUP;
  float* Wih_lds = smem + L_WIH;
  float* Hbuf    = smem + L_HBUF;
  float* redsc   = smem + L_RED;
  float* ci16    = smem + L_CI;
  int* gidx_lds  = (int*)(smem + L_GIDX);
  int* ql_j      = (int*)(smem + L_QLJ);
  int* ql_q      = (int*)(smem + L_QLQ);
  int* nq_sp     = (int*)(smem + L_NQ);

  const int g = blockIdx.x;
  const int tid = threadIdx.x;
  unsigned* flags = (unsigned*)(ws + BAR_OFF);
  unsigned* gen = flags + 4096;
  const int mmod = (g < 192) ? (g >> 6) : 0;
  const int loc0 = (g & 63) * 16;
  const int bb = tid & 15;
  const int jg = (tid >> 4) & 7;
  const int kh = tid >> 7;
  const int kb = kh * 128;
  float h00 = 0.f, h01 = 0.f, h10 = 0.f, h11 = 0.f;

  if (g < 192) {
    const float* Wsrc = (mmod == 0) ? W11 : ((mmod == 1) ? W22 : W33);
    // stage W slice (16 x 1024 fp32) into LDS once
    #pragma unroll
    for (int i = 0; i < 16; ++i) {
      float4 v = *(const float4*)&Wsrc[(size_t)(loc0 + i) * 1024 + tid * 4];
      *(float4*)&W_lds[i * 1028 + tid * 4] = v;
    }
    if (mmod == 0) {
      Wih_lds[tid] = Wih[(loc0 + (tid >> 4)) * 16 + (tid & 15)];
    }
    if (mmod == 1 && tid < 16) {
      ci16[tid] = ctx[0] * Whc2[(loc0 + tid) * 2];
    }
    if (mmod != 0 && tid < 205) {
      const int* gsrc = (mmod == 1) ? id12_1 : id23_2;
      gidx_lds[tid] = gsrc[tid];
    }
    if (tid == 0) {
      int cnt = 0;
      if (mmod != 0) {
        const int* scat = (mmod == 1) ? id12_2 : id23_3;
        for (int q = 0; q < 205; ++q) {
          int jj = scat[q] - loc0;
          if (jj >= 0 && jj < 16) { ql_j[cnt] = jj; ql_q[cnt] = q; ++cnt; }
        }
      }
      *nq_sp = cnt;
    }
    if (!kh) {
      int gn0 = mmod * 1024 + loc0 + jg;
      h00 = h0[bb * 3072 + gn0];
      h01 = h0[(bb + 16) * 3072 + gn0];
      h10 = h0[bb * 3072 + gn0 + 8];
      h11 = h0[(bb + 16) * 3072 + gn0 + 8];
    }
  }
  __syncthreads();

  #pragma unroll 1
  for (int t = 0; t < 512; ++t) {
    const int p = t & 1;
    const float* thbuf_p = ws + THBUF_OFF + (size_t)p * 98304;
    float*       thbuf_n = ws + THBUF_OFF + (size_t)(p ^ 1) * 98304;
    const float* thT_p   = ws + THT_OFF + (size_t)p * 98304;
    float*       thT_n   = ws + THT_OFF + (size_t)(p ^ 1) * 98304;

    if (g < 192) {
      const float* thmod = thbuf_p + mmod * 1024;
      float4 pf[8];
      // zero coupling staging + prefetch chunk 0
      *(float4*)&coupf[tid * 4] = make_float4(0.f, 0.f, 0.f, 0.f);
      LOADPF(0);
      __syncthreads();
      // ---- sparse couplings ----
      if (mmod != 0) {
        const int ntask = *nq_sp * 64;
        const float* Wsp = (mmod == 1) ? W12 : W23;
        const int rbase = (mmod == 1) ? 0 : 1024;
        for (int task = tid; task < ntask; task += 256) {
          int kh2 = task & 1;
          int b = (task >> 1) & 31;
          int qi = task >> 6;
          int q = ql_q[qi], jj = ql_j[qi];
          int p0 = kh2 ? 103 : 0;
          int p1 = kh2 ? 205 : 103;
          float v = 0.0f;
          for (int pp = p0; pp < p1; ++pp) {
            v += Wsp[q * 205 + pp] * thT_p[(rbase + gidx_lds[pp]) * 32 + b];
          }
          coupf[kh2 * 512 + jj * 32 + b] = v;
        }
      }
      WRITEBUF(0);
      // ---- main GEMM: W from LDS, th double-buffered ----
      float acc00 = 0.f, acc01 = 0.f, acc10 = 0.f, acc11 = 0.f;
      #pragma unroll 1
      for (int c = 0; c < 4; ++c) {
        __syncthreads();
        if (c < 3) LOADPF(c + 1);
        COMPUTE_CHUNK(c);
        if (c < 3) WRITEBUF(c + 1);
      }
      __syncthreads();
      if (kh) {
        int l = (tid - 128) * 4;
        redsc[l] = acc00; redsc[l + 1] = acc01;
        redsc[l + 2] = acc10; redsc[l + 3] = acc11;
      }
      __syncthreads();
      if (!kh) {
        acc00 += redsc[tid * 4];     acc01 += redsc[tid * 4 + 1];
        acc10 += redsc[tid * 4 + 2]; acc11 += redsc[tid * 4 + 3];
        const float* xTt = ws + XT_OFF + t * 512;
        const float* wnt = ws + WN_OFF + t * 3072;
        float accs[4] = {acc00, acc01, acc10, acc11};
        float hs[4] = {h00, h01, h10, h11};
        #pragma unroll
        for (int js = 0; js < 2; ++js) {
          int j = jg + js * 8;
          int gn = mmod * 1024 + loc0 + j;
          #pragma unroll
          for (int bs = 0; bs < 2; ++bs) {
            int b = bb + bs * 16;
            float dot = accs[js * 2 + bs];
            float extra;
            if (mmod == 0) {
              extra = 0.f;
              #pragma unroll
              for (int ii = 0; ii < 16; ++ii)
                extra += xTt[b * 16 + ii] * Wih_lds[j * 16 + ii];
            } else {
              float cp = coupf[j * 32 + b] + coupf[512 + j * 32 + b];
              extra = (mmod == 1) ? cp * ci16[j] : cp;
            }
            float hv = hs[js * 2 + bs];
            hv = hv + (dot + extra + wnt[gn] - hv) / 10.0f;
            hs[js * 2 + bs] = hv;
            float tv = tanhf(hv);
            thbuf_n[b * 3072 + gn] = tv;
            thT_n[gn * 32 + b] = tv;
            Hbuf[(j * 32 + b) * 4 + (t & 3)] = tv;
          }
        }
        h00 = hs[0]; h01 = hs[1]; h10 = hs[2]; h11 = hs[3];
      }
      if ((t & 3) == 3) {
        __syncthreads();
        #pragma unroll
        for (int r = 0; r < 2; ++r) {
          int o = tid * 2 + r;
          int j = o >> 5, b = o & 31;
          size_t gn = (size_t)(mmod * 1024 + loc0 + j);
          float4 v = *(const float4*)&Hbuf[o * 4];
          *(float4*)&out[((size_t)b * 3072 + gn) * 512 + (t - 3)] = v;
        }
      }
    } else {
      // ---- aux WGs: y and yr readouts ----
      const int w = tid >> 6, lane = tid & 63;
      const int gw = (g - 192) * 4 + w;
      float* auxb = coupf;  // aux-only alias
      for (int s = 0; s < 4; ++s) {
        const int u = gw + s * 256;
        if (u >= 800) break;
        float a0 = 0.f, a1 = 0.f, a2 = 0.f, a3 = 0.f;
        if (u < 768) {
          const int mm = u >> 8;
          const int rem = u & 255;
          const int b = rem >> 3;
          const int rr0 = (rem & 7) * 4;
          const float* Wr = (mm == 0) ? Wr1 : ((mm == 1) ? Wr2 : Wr3);
          const float* trow = thbuf_p + b * 3072 + mm * 1024;
          #pragma unroll
          for (int it = 0; it < 4; ++it) {
            int k = it * 256 + lane * 4;
            float4 tv = *(const float4*)(trow + k);
            float4 q0 = *(const float4*)&Wr[(rr0 + 0) * 1024 + k];
            float4 q1 = *(const float4*)&Wr[(rr0 + 1) * 1024 + k];
            float4 q2 = *(const float4*)&Wr[(rr0 + 2) * 1024 + k];
            float4 q3 = *(const float4*)&Wr[(rr0 + 3) * 1024 + k];
            a0 += tv.x*q0.x + tv.y*q0.y + tv.z*q0.z + tv.w*q0.w;
            a1 += tv.x*q1.x + tv.y*q1.y + tv.z*q1.z + tv.w*q1.w;
            a2 += tv.x*q2.x + tv.y*q2.y + tv.z*q2.z + tv.w*q2.w;
            a3 += tv.x*q3.x + tv.y*q3.y + tv.z*q3.z + tv.w*q3.w;
          }
        } else {
          const int b = u - 768;
          const float* trow = thbuf_p + b * 3072 + 2048;
          #pragma unroll
          for (int it = 0; it < 4; ++it) {
            int k = it * 256 + lane * 4;
            float4 tv = *(const float4*)(trow + k);
            float4 q0 = *(const float4*)&Who[k];
            a0 += tv.x*q0.x + tv.y*q0.y + tv.z*q0.z + tv.w*q0.w;
          }
        }
        #pragma unroll
        for (int off = 32; off > 0; off >>= 1) {
          a0 += __shfl_xor(a0, off);
          a1 += __shfl_xor(a1, off);
          a2 += __shfl_xor(a2, off);
          a3 += __shfl_xor(a3, off);
        }
        if (lane == 0) {
          int base = ((w * 4 + s) * 4) * 4 + (t & 3);
          auxb[base] = tanhf(a0);
          if (u < 768) {
            auxb[base + 4]  = tanhf(a1);
            auxb[base + 8]  = tanhf(a2);
            auxb[base + 12] = tanhf(a3);
          }
        }
      }
      if ((t & 3) == 3) {
        __syncthreads();
        int s = lane >> 2, rv = lane & 3;
        if (lane < 16) {
          int u = gw + s * 256;
          if (u < 768) {
            int mm = u >> 8, rem = u & 255, b = rem >> 3, rr = (rem & 7) * 4 + rv;
            float4 v = *(const float4*)&auxb[((w * 4 + s) * 4 + rv) * 4];
            *(float4*)&out[(size_t)YR0_OFF + ((size_t)(b * 32 + rr) * 3 + mm) * 512 + (t - 3)] = v;
          } else if (u < 800 && rv == 0) {
            float4 v = *(const float4*)&auxb[((w * 4 + s) * 4) * 4];
            *(float4*)&out[(size_t)Y0_OFF + (size_t)(u - 768) * 512 + (t - 3)] = v;
          }
        }
      }
    }
    flagBarrier(flags, gen, g, tid, (unsigned)(t + 1));
  }
}

extern "C" void kernel_launch(void* const* d_in, const int* in_sizes, int n_in,
                              void* d_out, int out_size, void* d_ws, size_t ws_size,
                              hipStream_t stream) {
  (void)in_sizes; (void)n_in; (void)out_size; (void)ws_size;
  const float* x    = (const float*)d_in[0];
  const float* h0   = (const float*)d_in[1];
  const float* ctx  = (const float*)d_in[2];
  const float* iWN  = (const float*)d_in[3];
  const float* Wih  = (const float*)d_in[4];
  const float* W11  = (const float*)d_in[5];
  const float* W22  = (const float*)d_in[6];
  const float* W33  = (const float*)d_in[7];
  const float* W12  = (const float*)d_in[8];
  const float* W23  = (const float*)d_in[9];
  const float* Who  = (const float*)d_in[10];
  const float* Whc2 = (const float*)d_in[11];
  const float* Wr1  = (const float*)d_in[12];
  const float* Wr2  = (const float*)d_in[13];
  const float* Wr3  = (const float*)d_in[14];
  const int* id12_1 = (const int*)d_in[15];
  const int* id12_2 = (const int*)d_in[16];
  const int* id23_2 = (const int*)d_in[17];
  const int* id23_3 = (const int*)d_in[18];
  float* ws = (float*)d_ws;
  float* out = (float*)d_out;

  hipFuncSetAttribute(reinterpret_cast<const void*>(rnn_main),
                      hipFuncAttributeMaxDynamicSharedMemorySize, SMEM_BYTES);
  hipLaunchKernelGGL(prep1, dim3(512), dim3(256), 0, stream, x, h0, ws);
  hipLaunchKernelGGL(prep2, dim3(12), dim3(256), 0, stream, iWN, ws);
  hipLaunchKernelGGL(rnn_main, dim3(256), dim3(256), SMEM_BYTES, stream,
                     Wih, W11, W22, W33, W12, W23, Who, Whc2, Wr1, Wr2, Wr3,
                     id12_1, id12_2, id23_2, id23_3, ctx, h0, ws, out);
}